// Round 5
// baseline (164.474 us; speedup 1.0000x reference)
//
#include <hip/hip_runtime.h>
#include <math.h>

// Problem constants (fixed by setup_inputs)
#define D     1024   // gd = dn = de
#define N1    48     // n1 = n2
#define E1    192    // e1 = e2
#define NOUT  2304   // n1*n2 = output dim
#define NE    36864  // e1*e2
#define KS    8      // K-split factor (K=128 per block slice)

#define MP_TILES 9       // 3x3 tiles of 16x16 for Mp (48x48)
#define ME_TILES 144     // 12x12 tiles for Me (192x192)

// K1 grid layout
#define COEFF_ITEMS  (2 * D)                 // 2048 coeff rows
#define MZERO_ITEMS  (NOUT * NOUT / 4096)    // 1296 chunks of 4096 floats
#define WSZERO_ITEMS 10                      // 10*4096 = 40960 >= 39321 floats
#define K1_GRID      (COEFF_ITEMS + MZERO_ITEMS + WSZERO_ITEMS)

#define K2_GRID      ((MP_TILES + ME_TILES) * KS)   // 1224

__device__ __forceinline__ float act(float x) {
    float sp = fmaxf(x, 0.f) + log1pf(expf(-fabsf(x)));   // stable softplus
    return fmaxf(sp - 0.5f, 0.f);
}

// ---------------------------------------------------------------------------
// K1: coeff = tanh(W @ gw + b) (blocks [0,2048)), zero M (blocks
// [2048,3344)), zero accumulators + tile counters (blocks [3344,3354)).
// The zero work overlaps the W reads; all of it must land before K2.
// ---------------------------------------------------------------------------
__global__ void prep_kernel(const float* __restrict__ Wn, const float* __restrict__ bn,
                            const float* __restrict__ We, const float* __restrict__ be,
                            const float* __restrict__ gw, float* __restrict__ coeff,
                            float* __restrict__ M, float* __restrict__ zacc) {
    int bid = blockIdx.x;
    int t = threadIdx.x;
    if (bid < COEFF_ITEMS) {
        const float* W; const float* b; int d;
        if (bid < D) { W = Wn; b = bn; d = bid; }
        else         { W = We; b = be; d = bid - D; }
        float4 w = *(const float4*)(W + (size_t)d * D + t * 4);
        float4 g = *(const float4*)(gw + t * 4);
        float s = w.x * g.x + w.y * g.y + w.z * g.z + w.w * g.w;
        #pragma unroll
        for (int off = 32; off > 0; off >>= 1) s += __shfl_down(s, off);
        __shared__ float red[4];
        if ((t & 63) == 0) red[t >> 6] = s;
        __syncthreads();
        if (t == 0) coeff[bid] = tanhf(red[0] + red[1] + red[2] + red[3] + b[d]);
    } else if (bid < COEFF_ITEMS + MZERO_ITEMS) {
        size_t base = (size_t)(bid - COEFF_ITEMS) * 4096 + t * 4;
        float4 z = make_float4(0.f, 0.f, 0.f, 0.f);
        #pragma unroll
        for (int p = 0; p < 4; p++) *(float4*)(M + base + p * 1024) = z;
    } else {
        size_t base = (size_t)(bid - COEFF_ITEMS - MZERO_ITEMS) * 4096 + t * 4;
        float4 z = make_float4(0.f, 0.f, 0.f, 0.f);
        #pragma unroll
        for (int p = 0; p < 4; p++) *(float4*)(zacc + base + p * 1024) = z;
    }
}

// ---------------------------------------------------------------------------
// K2: split-K affinity + last-block-finisher scatter, one launch, no grid
// barrier (R4's cooperative launch was silently rejected -> all-zero out).
//   Each block: 16x16 tile, K=128 slice -> device-scope atomicAdd of the raw
//   dot partial into the per-element accumulator (zeroed by K1), then
//   __threadfence + per-tile arrival counter. The 8th arriver re-reads the
//   summed values with agent-scope atomic loads (cross-XCD coherent), applies
//   softplus/relu, and scatters into M (zeroed one kernel boundary earlier):
//     Me tile: M[h2[b2]*48+h1[b1], t2[b2]*48+t1[b1]] += v   (skip v==0)
//     Mp tile: M[r,r] += v
// Deadlock-free: no block ever waits; dispatch order irrelevant.
// ---------------------------------------------------------------------------
__global__ __launch_bounds__(256)
void affinity_scatter_kernel(const float* __restrict__ x1, const float* __restrict__ x2,
                             const float* __restrict__ ef1, const float* __restrict__ ef2,
                             const float* __restrict__ coeff,
                             const int* __restrict__ ei1, const int* __restrict__ ei2,
                             float* __restrict__ Mp_acc, float* __restrict__ Me_acc,
                             int* __restrict__ cnt, float* __restrict__ M) {
    __shared__ float As[16][68];   // +4 pad: 16B-aligned ds_read_b128, bank stride 4
    __shared__ float Bs[16][68];
    __shared__ int isLast;
    int bid = blockIdx.x;
    int t = threadIdx.x;

    const float *A, *B, *cf; float* accbuf; int tile, ks, ncols, tiles_x, cntIdx; bool isMp;
    if (bid < MP_TILES * KS) {
        tile = bid >> 3; ks = bid & 7;
        A = x1; B = x2; cf = coeff; accbuf = Mp_acc;
        ncols = N1; tiles_x = 3; cntIdx = tile; isMp = true;
    } else {
        int b = bid - MP_TILES * KS;
        tile = b >> 3; ks = b & 7;
        A = ef1; B = ef2; cf = coeff + D; accbuf = Me_acc;
        ncols = E1; tiles_x = 12; cntIdx = MP_TILES + tile; isMp = false;
    }
    int ty = tile / tiles_x, tx = tile - ty * tiles_x;
    int r  = t >> 4;          // 0..15: tile row (load + compute)
    int cb = (t & 15) << 2;   // 0..60: k-column base for loads
    int cc = t & 15;          // 0..15: tile col (compute)
    size_t rowA = (size_t)(ty * 16 + r);
    size_t rowB = (size_t)(tx * 16 + r);
    float acc = 0.f;
    #pragma unroll
    for (int ch = 0; ch < 2; ch++) {
        int k0 = ks * 128 + ch * 64;
        float4 a = *(const float4*)(A + rowA * D + k0 + cb);
        float4 c = *(const float4*)(cf + k0 + cb);
        float4 b = *(const float4*)(B + rowB * D + k0 + cb);
        *(float4*)&As[r][cb] = make_float4(a.x * c.x, a.y * c.y, a.z * c.z, a.w * c.w);
        *(float4*)&Bs[r][cb] = b;
        __syncthreads();
        #pragma unroll
        for (int kk = 0; kk < 64; kk += 4) {
            float4 av = *(const float4*)&As[r][kk];
            float4 bv = *(const float4*)&Bs[cc][kk];
            acc = fmaf(av.x, bv.x, acc);
            acc = fmaf(av.y, bv.y, acc);
            acc = fmaf(av.z, bv.z, acc);
            acc = fmaf(av.w, bv.w, acc);
        }
        __syncthreads();
    }

    int elem = (ty * 16 + r) * ncols + tx * 16 + cc;
    atomicAdd(&accbuf[elem], acc);      // device-scope by default on gfx950
    __threadfence();                    // my add visible before my arrival below
    __syncthreads();                    // all 256 adds fenced before thread 0 arrives
    if (t == 0) isLast = (atomicAdd(&cnt[cntIdx], 1) == KS - 1);
    __syncthreads();
    if (!isLast) return;

    // ---- finisher: all KS partials for this tile have landed ----
    float s = __hip_atomic_load(&accbuf[elem], __ATOMIC_RELAXED, __HIP_MEMORY_SCOPE_AGENT);
    float v = act(s);
    if (v > 0.f) {
        if (isMp) {
            atomicAdd(M + (size_t)elem * NOUT + elem, v);
        } else {
            int b2 = ty * 16 + r, b1 = tx * 16 + cc;
            int rr  = ei2[b2]      * N1 + ei1[b1];
            int ccc = ei2[E1 + b2] * N1 + ei1[E1 + b1];
            atomicAdd(M + (size_t)rr * NOUT + ccc, v);
        }
    }
}

extern "C" void kernel_launch(void* const* d_in, const int* in_sizes, int n_in,
                              void* d_out, int out_size, void* d_ws, size_t ws_size,
                              hipStream_t stream) {
    const float* x1  = (const float*)d_in[0];
    const float* x2  = (const float*)d_in[1];
    const float* ef1 = (const float*)d_in[2];
    const float* ef2 = (const float*)d_in[3];
    const float* gw  = (const float*)d_in[4];
    const float* Wn  = (const float*)d_in[5];
    const float* bn  = (const float*)d_in[6];
    const float* We  = (const float*)d_in[7];
    const float* be  = (const float*)d_in[8];
    const int*   ei1 = (const int*)d_in[9];
    const int*   ei2 = (const int*)d_in[10];

    float* M  = (float*)d_out;
    float* ws = (float*)d_ws;
    float* coeff  = ws;                       // 2048 floats
    float* Mp_acc = ws + 2048;                // 2304 floats
    float* Me_acc = Mp_acc + NOUT;            // 36864 floats
    int*   cnt    = (int*)(Me_acc + NE);      // 153 ints
    // zacc zero range covers Mp_acc..cnt (39321 floats; we clear 40960)

    prep_kernel<<<K1_GRID, 256, 0, stream>>>(Wn, bn, We, be, gw, coeff, M, Mp_acc);
    affinity_scatter_kernel<<<K2_GRID, 256, 0, stream>>>(
        x1, x2, ef1, ef2, coeff, ei1, ei2, Mp_acc, Me_acc, cnt, M);
}

// Round 6
// 95.944 us; speedup vs baseline: 1.7143x; 1.7143x over previous
//
#include <hip/hip_runtime.h>
#include <math.h>

// Problem constants (fixed by setup_inputs)
#define D     1024   // gd = dn = de
#define N1    48     // n1 = n2
#define E1    192    // e1 = e2
#define NOUT  2304   // n1*n2 = output dim

// K1 grid layout
#define COEFF_ITEMS  (2 * D)                 // 2048 coeff rows
#define MZERO_ITEMS  (NOUT * NOUT / 4096)    // 1296 chunks of 4096 floats
#define K1_GRID      (COEFF_ITEMS + MZERO_ITEMS)

// K2 grid layout: 8x8 output tiles, full K per block
#define MP_TILES 36      // 6x6 tiles (48x48)
#define ME_TILES 576     // 24x24 tiles (192x192)
#define K2_GRID  (MP_TILES + ME_TILES)       // 612

__device__ __forceinline__ float act(float x) {
    float sp = fmaxf(x, 0.f) + log1pf(expf(-fabsf(x)));   // stable softplus
    return fmaxf(sp - 0.5f, 0.f);
}

// ---------------------------------------------------------------------------
// K1: coeff = tanh(W @ gw + b) (blocks [0,2048)) + zero M (blocks
// [2048,3344)). Both must complete before K2 (coeff feeds affinity; M must
// be zero before scatter atomics). One boundary = the only cheap cross-block
// sync on gfx950 (R5: device-scope atomic finisher cost 78 us; R4: coop
// launch silently rejected).
// ---------------------------------------------------------------------------
__global__ void prep_kernel(const float* __restrict__ Wn, const float* __restrict__ bn,
                            const float* __restrict__ We, const float* __restrict__ be,
                            const float* __restrict__ gw, float* __restrict__ coeff,
                            float* __restrict__ M) {
    int bid = blockIdx.x;
    int t = threadIdx.x;
    if (bid < COEFF_ITEMS) {
        const float* W; const float* b; int d;
        if (bid < D) { W = Wn; b = bn; d = bid; }
        else         { W = We; b = be; d = bid - D; }
        float4 w = *(const float4*)(W + (size_t)d * D + t * 4);
        float4 g = *(const float4*)(gw + t * 4);
        float s = w.x * g.x + w.y * g.y + w.z * g.z + w.w * g.w;
        #pragma unroll
        for (int off = 32; off > 0; off >>= 1) s += __shfl_down(s, off);
        __shared__ float red[4];
        if ((t & 63) == 0) red[t >> 6] = s;
        __syncthreads();
        if (t == 0) coeff[bid] = tanhf(red[0] + red[1] + red[2] + red[3] + b[d]);
    } else {
        size_t base = (size_t)(bid - COEFF_ITEMS) * 4096 + t * 4;
        float4 z = make_float4(0.f, 0.f, 0.f, 0.f);
        #pragma unroll
        for (int p = 0; p < 4; p++) *(float4*)(M + base + p * 1024) = z;
    }
}

// ---------------------------------------------------------------------------
// K2: one block per 8x8 output tile, FULL K=1024 (4 LDS chunks of 256,
// 4-way K-split across the 256 threads), LDS reduce, act(), then the block
// scatters its own values straight into M. No partials, no cross-block sync.
//   blocks [0,36):   Mp tiles -> M[flat,flat] += v, flat = i*48+j
//   blocks [36,612): Me tiles -> M[h2[i]*48+h1[j], t2[i]*48+t1[j]] += v
// Thread map: oc = t&63 -> (r=oc>>3, c=oc&7) output in tile; kq = t>>6 is
// the K-quadrant (64 K per chunk per thread). coeff folded into As at load.
// Row stride 260 floats: 16B-aligned rows (1040 B), bank stride 4 between
// rows -> compute reads are 8-row broadcast groups, conflict-free.
// ---------------------------------------------------------------------------
__global__ __launch_bounds__(256)
void affinity_scatter_kernel(const float* __restrict__ x1, const float* __restrict__ x2,
                             const float* __restrict__ ef1, const float* __restrict__ ef2,
                             const float* __restrict__ coeff,
                             const int* __restrict__ ei1, const int* __restrict__ ei2,
                             float* __restrict__ M) {
    __shared__ float As[8][260];
    __shared__ float Bs[8][260];
    __shared__ float red[256];
    int bid = blockIdx.x;
    int t = threadIdx.x;

    const float *A, *B, *cf; int tile, tiles_x; bool isMp;
    if (bid < MP_TILES) {
        A = x1; B = x2; cf = coeff; tile = bid; tiles_x = 6; isMp = true;
    } else {
        A = ef1; B = ef2; cf = coeff + D; tile = bid - MP_TILES; tiles_x = 24; isMp = false;
    }
    int ty = tile / tiles_x, tx = tile - ty * tiles_x;

    int oc = t & 63;          // output element in tile: r=oc>>3, c=oc&7
    int r  = oc >> 3, c = oc & 7;
    int kq = t >> 6;          // K quadrant (0..3)
    int lrow = t >> 6;        // load row group base (0..3), +4 for second f4
    int lcol = (t & 63) << 2; // load column (floats)

    float acc = 0.f;
    for (int ch = 0; ch < 4; ch++) {
        int k0 = ch * 256;
        // stage: 8 rows x 256 floats per buffer; each thread 2 f4 per buffer
        float4 c4 = *(const float4*)(cf + k0 + lcol);
        float4 a0 = *(const float4*)(A + (size_t)(ty * 8 + lrow)     * D + k0 + lcol);
        float4 a1 = *(const float4*)(A + (size_t)(ty * 8 + lrow + 4) * D + k0 + lcol);
        float4 b0 = *(const float4*)(B + (size_t)(tx * 8 + lrow)     * D + k0 + lcol);
        float4 b1 = *(const float4*)(B + (size_t)(tx * 8 + lrow + 4) * D + k0 + lcol);
        *(float4*)&As[lrow][lcol]     = make_float4(a0.x * c4.x, a0.y * c4.y, a0.z * c4.z, a0.w * c4.w);
        *(float4*)&As[lrow + 4][lcol] = make_float4(a1.x * c4.x, a1.y * c4.y, a1.z * c4.z, a1.w * c4.w);
        *(float4*)&Bs[lrow][lcol]     = b0;
        *(float4*)&Bs[lrow + 4][lcol] = b1;
        __syncthreads();
        int kb = kq * 64;     // this thread's 64-K slice within the chunk
        #pragma unroll
        for (int m = 0; m < 64; m += 4) {
            float4 av = *(const float4*)&As[r][kb + m];
            float4 bv = *(const float4*)&Bs[c][kb + m];
            acc = fmaf(av.x, bv.x, acc);
            acc = fmaf(av.y, bv.y, acc);
            acc = fmaf(av.z, bv.z, acc);
            acc = fmaf(av.w, bv.w, acc);
        }
        __syncthreads();
    }

    red[t] = acc;             // red[kq*64 + oc]
    __syncthreads();
    if (t < 64) {
        float s = red[t] + red[t + 64] + red[t + 128] + red[t + 192];
        float v = act(s);
        if (v > 0.f) {
            int i = ty * 8 + (t >> 3);   // row in Mp/Me
            int j = tx * 8 + (t & 7);    // col in Mp/Me
            if (isMp) {
                size_t flat = (size_t)i * N1 + j;     // diag index in [0,2304)
                atomicAdd(M + flat * NOUT + flat, v);
            } else {
                int rr = ei2[i]      * N1 + ei1[j];        // heads
                int cc = ei2[E1 + i] * N1 + ei1[E1 + j];   // tails
                atomicAdd(M + (size_t)rr * NOUT + cc, v);
            }
        }
    }
}

extern "C" void kernel_launch(void* const* d_in, const int* in_sizes, int n_in,
                              void* d_out, int out_size, void* d_ws, size_t ws_size,
                              hipStream_t stream) {
    const float* x1  = (const float*)d_in[0];
    const float* x2  = (const float*)d_in[1];
    const float* ef1 = (const float*)d_in[2];
    const float* ef2 = (const float*)d_in[3];
    const float* gw  = (const float*)d_in[4];
    const float* Wn  = (const float*)d_in[5];
    const float* bn  = (const float*)d_in[6];
    const float* We  = (const float*)d_in[7];
    const float* be  = (const float*)d_in[8];
    const int*   ei1 = (const int*)d_in[9];
    const int*   ei2 = (const int*)d_in[10];

    float* M     = (float*)d_out;
    float* coeff = (float*)d_ws;   // 2048 floats

    prep_kernel<<<K1_GRID, 256, 0, stream>>>(Wn, bn, We, be, gw, coeff, M);
    affinity_scatter_kernel<<<K2_GRID, 256, 0, stream>>>(
        x1, x2, ef1, ef2, coeff, ei1, ei2, M);
}